// Round 4
// baseline (80.887 us; speedup 1.0000x reference)
//
#include <hip/hip_runtime.h>

// Problem constants (from reference setup_inputs)
#define Bn 8
#define Nn 128
#define Fdim 32     // input feature dim F
#define Sdim 8      // edge feature dim S
#define Hdim 32     // kernel-network hidden width H
#define Fout 32     // output channels F_

typedef float  f32x4  __attribute__((ext_vector_type(4)));
typedef short  bf16x8 __attribute__((ext_vector_type(8)));

#define PITCH 136   // bf16 row pitch for hT/nfT: 272B = 17*16B (aligned, bank-spread)

__device__ __forceinline__ unsigned short f2bf(float x) {
    union { float f; unsigned u; } v; v.f = x;
    return (unsigned short)((v.u + 0x7FFFu + ((v.u >> 16) & 1u)) >> 16);
}
__device__ __forceinline__ unsigned pack2(float lo, float hi) {
    return (unsigned)f2bf(lo) | ((unsigned)f2bf(hi) << 16);
}

// One block per (a,b); 256 threads; 2 barriers.
// out[a,b,c] = inv * ( sum_{h,f} T'[h,f]*Wout[h,c*32+f] + sum_f q'[f]*bout[c*32+f] ) + bias[c]
//   T'[h,f] = sum_i fltr[i]*relu(ef[a,b,i,:]@W0+b0)[h]*nf[a,i,f]   (bf16 MFMA, f32 accum)
//   q'[f]   = sum_i fltr[i]*nf[a,i,f]
//   inv     = 1/max(sum_i fltr[i], 1e-11)
__global__ __launch_bounds__(256, 4) void ecc_kernel(
    const float* __restrict__ nf,    // (B,N,F)
    const float* __restrict__ fltr,  // (B,N,N)
    const float* __restrict__ ef,    // (B,N,N,S)
    const float* __restrict__ W0,    // (S,H)
    const float* __restrict__ b0,    // (H)
    const float* __restrict__ Wout,  // (H, F_*F)
    const float* __restrict__ bout,  // (F_*F)
    const float* __restrict__ bias,  // (F_)
    float* __restrict__ out)         // (B,N,F_)
{
    __shared__ __align__(16) unsigned short hT[Hdim * PITCH];  // h^T[h][i] bf16 (fltr-scaled relu)
    __shared__ __align__(16) unsigned short nT[Fdim * PITCH];  // nf^T[f][i] bf16
    __shared__ __align__(16) float Ts[Hdim * 36];              // T'[h][f] f32, pitch 36
    __shared__ __align__(16) float qp[Nn];                     // q partials (4 quarters x 32 f)
    __shared__ float inv_s;

    const int t    = threadIdx.x;
    const int blk  = blockIdx.x;       // a*N + b
    const int a    = blk >> 7;
    const int hcol = t & 31;

    const float* __restrict__ nfa  = nf   + (size_t)a   * (Nn * Fdim);
    const float* __restrict__ frow = fltr + (size_t)blk * Nn;
    const float* __restrict__ erow = ef   + (size_t)blk * (Nn * Sdim);

    // ---- W0 column + b0 in registers (per-thread column hcol) ----
    float w0r[Sdim];
    #pragma unroll
    for (int s = 0; s < Sdim; ++s) w0r[s] = W0[s * Hdim + hcol];
    const float b0r = b0[hcol];

    // ---- inv = 1/sum(fltr row)  (wave 0; visible at B1) ----
    if (t < 64) {
        float s = frow[t] + frow[t + 64];
        #pragma unroll
        for (int off = 32; off > 0; off >>= 1) s += __shfl_down(s, off);
        if (t == 0) inv_s = 1.0f / fmaxf(s, 1e-11f);
    }

    // ---- stage nf^T as bf16 (packed-pair writes; global reads coalesced) ----
    {
        const int f = t & 31, iseg = t >> 5;           // 32 f x 8 i-segments of 16
        unsigned* dst = (unsigned*)&nT[f * PITCH + iseg * 16];
        #pragma unroll 4
        for (int k = 0; k < 16; k += 2) {
            const int i = iseg * 16 + k;
            const float x0 = nfa[i * Fdim + f];
            const float x1 = nfa[(i + 1) * Fdim + f];
            dst[k >> 1] = pack2(x0, x1);
        }
    }

    // ---- h^T: hT[h][i] = bf16( relu(ef[i,:]@W0+b0)[h] * fltr[i] ), ef/fltr from global ----
    {
        const int il = t >> 5;                         // 0..7, 16 i's each
        unsigned* dst = (unsigned*)&hT[hcol * PITCH + il * 16];
        #pragma unroll 2
        for (int k = 0; k < 16; k += 2) {
            const int i0 = il * 16 + k;
            const float4 e0a = *(const float4*)(erow + i0 * Sdim);
            const float4 e0b = *(const float4*)(erow + i0 * Sdim + 4);
            const float4 e1a = *(const float4*)(erow + i0 * Sdim + 8);
            const float4 e1b = *(const float4*)(erow + i0 * Sdim + 12);
            float a0 = b0r, a1 = b0r;
            a0 += e0a.x * w0r[0] + e0a.y * w0r[1] + e0a.z * w0r[2] + e0a.w * w0r[3];
            a0 += e0b.x * w0r[4] + e0b.y * w0r[5] + e0b.z * w0r[6] + e0b.w * w0r[7];
            a1 += e1a.x * w0r[0] + e1a.y * w0r[1] + e1a.z * w0r[2] + e1a.w * w0r[3];
            a1 += e1b.x * w0r[4] + e1b.y * w0r[5] + e1b.z * w0r[6] + e1b.w * w0r[7];
            const float h0 = fmaxf(a0, 0.0f) * frow[i0];
            const float h1 = fmaxf(a1, 0.0f) * frow[i0 + 1];
            dst[k >> 1] = pack2(h0, h1);
        }
    }

    // ---- q' partials (upper 128 threads; global reads, no LDS reads) ----
    if (t >= 128) {
        const int f = t & 31, qr = (t >> 5) & 3;
        float q = 0.f;
        #pragma unroll 4
        for (int k = 0; k < 32; ++k) {
            const int i = qr * 32 + k;
            q += frow[i] * nfa[i * Fdim + f];
        }
        qp[qr * 32 + f] = q;
    }
    __syncthreads();                                   // B1

    // ---- T' via MFMA: wave w owns 16x16 tile (mt=w>>1, nt=w&1); K=128 in 4 steps ----
    {
        const int w  = t >> 6, l = t & 63;
        const int lr = l & 15, lg = l >> 4;
        const int mt = w >> 1, nt = w & 1;
        f32x4 acc = {0.f, 0.f, 0.f, 0.f};
        #pragma unroll
        for (int kt = 0; kt < 4; ++kt) {
            const bf16x8 av = *(const bf16x8*)&hT[(mt * 16 + lr) * PITCH + kt * 32 + lg * 8];
            const bf16x8 bv = *(const bf16x8*)&nT[(nt * 16 + lr) * PITCH + kt * 32 + lg * 8];
            acc = __builtin_amdgcn_mfma_f32_16x16x32_bf16(av, bv, acc, 0, 0, 0);
        }
        // C/D layout: col = lane&15, row = (lane>>4)*4 + reg   [m89-verified]
        #pragma unroll
        for (int r = 0; r < 4; ++r)
            Ts[(mt * 16 + lg * 4 + r) * 36 + nt * 16 + lr] = acc[r];
    }
    __syncthreads();                                   // B2

    // ---- epilogue: out[c] = inv*(Ts.Wout + q'.bout) + bias  (f32 VALU) ----
    // lane layout: c = t>>3, f4 = t&7 -> Wout reads contiguous 128B per 8 lanes per h
    {
        const int c = t >> 3, f4 = t & 7;
        const float* wbase = Wout + (size_t)c * Fdim + f4 * 4;
        float partial = 0.f;
        #pragma unroll 8
        for (int h = 0; h < Hdim; ++h) {
            const float4 wv = *(const float4*)(wbase + (size_t)h * (Fout * Fdim));
            const float4 tv = *(const float4*)&Ts[h * 36 + f4 * 4];
            partial += tv.x * wv.x + tv.y * wv.y + tv.z * wv.z + tv.w * wv.w;
        }
        {
            const float4 q0 = *(const float4*)&qp[f4 * 4];
            const float4 q1 = *(const float4*)&qp[32 + f4 * 4];
            const float4 q2 = *(const float4*)&qp[64 + f4 * 4];
            const float4 q3 = *(const float4*)&qp[96 + f4 * 4];
            const float4 bv = *(const float4*)(bout + (size_t)c * Fdim + f4 * 4);
            partial += (q0.x + q1.x + q2.x + q3.x) * bv.x;
            partial += (q0.y + q1.y + q2.y + q3.y) * bv.y;
            partial += (q0.z + q1.z + q2.z + q3.z) * bv.z;
            partial += (q0.w + q1.w + q2.w + q3.w) * bv.w;
        }
        partial += __shfl_down(partial, 4, 8);
        partial += __shfl_down(partial, 2, 8);
        partial += __shfl_down(partial, 1, 8);
        if (f4 == 0)
            out[(size_t)blk * Fout + c] = partial * inv_s + bias[c];
    }
}

extern "C" void kernel_launch(void* const* d_in, const int* in_sizes, int n_in,
                              void* d_out, int out_size, void* d_ws, size_t ws_size,
                              hipStream_t stream) {
    const float* nf   = (const float*)d_in[0];
    const float* fltr = (const float*)d_in[1];
    const float* ef   = (const float*)d_in[2];
    const float* W0   = (const float*)d_in[3];
    const float* b0   = (const float*)d_in[4];
    const float* Wout = (const float*)d_in[5];
    const float* bout = (const float*)d_in[6];
    const float* bias = (const float*)d_in[7];
    float* out = (float*)d_out;

    ecc_kernel<<<dim3(Bn * Nn), dim3(256), 0, stream>>>(
        nf, fltr, ef, W0, b0, Wout, bout, bias, out);
}